// Round 8
// baseline (191.774 us; speedup 1.0000x reference)
//
#include <hip/hip_runtime.h>
#include <cfloat>

// Problem constants (fixed by the reference)
#define B_   8
#define C_   256
#define HW_  4096
#define BC_  2048      // B*C  (q/k/v row count)
#define TC_  768       // 3*C
#define NG_  16        // valid labels 0..15 (-1 invalid)
#define MAXG 320       // members[] capacity per group
#define UK0  682       // first x-row index used by k
#define NUQ  683       // x rows used by q: u in [0,682]
#define NUK  684       // x rows used by k: u in [682,1365]
#define NXU  1366      // x rows used by gram (q+k); xhi/xlo row count

// Gram MFMA: 128x128 tiles, 6x6 tile grid, split-K=8 pinned to XCDs
#define SPLITK 8
#define NT     6                    // ceil(684/128)
#define NTILES (NT * NT)            // 36
#define KSL    (HW_ / SPLITK)       // 512: K span per slice
#define NP1    (NUQ * NUK)          // one partial buffer (467172, /4 exact)

// Out GEMM / coef
#define MCAP  192      // supported group size (n ~ 120 +- 11; 192 is ~6.7 sigma)
#define CST   192      // coefh row stride (ushorts)
#define BKP   200      // Bt LDS row stride in ushorts (16B-aligned rows)

typedef __attribute__((ext_vector_type(8))) short short8;
typedef __attribute__((ext_vector_type(4))) float floatx4;

// ---------------------------------------------------------------------------
// Kernel 0: build label-group membership. One block per group; deterministic
// ordered build via block-wide scan (no atomics).
__global__ __launch_bounds__(256) void group_build_kernel(
    const int* __restrict__ labels, int* __restrict__ grp_n,
    int* __restrict__ members, int* __restrict__ posArr)
{
  __shared__ int lab[BC_];
  __shared__ int cnts[256];
  const int g = blockIdx.x;
  const int t = threadIdx.x;
  for (int idx = t; idx < BC_; idx += 256) lab[idx] = labels[idx];
  __syncthreads();

  const int base = t * 8;
  int cnt = 0;
#pragma unroll
  for (int k = 0; k < 8; k++) cnt += (lab[base + k] == g) ? 1 : 0;
  cnts[t] = cnt;
  for (int off = 1; off < 256; off <<= 1) {
    __syncthreads();
    const int v = (t >= off) ? cnts[t - off] : 0;
    __syncthreads();
    cnts[t] += v;
  }
  __syncthreads();
  int pos = cnts[t] - cnt;
  if (t == 255) grp_n[g] = cnts[255] < MAXG ? cnts[255] : MAXG;
#pragma unroll
  for (int k = 0; k < 8; k++) {
    const int i = base + k;
    if (lab[i] == g) {
      if (pos < MAXG) { members[g * MAXG + pos] = i; posArr[i] = pos; }
      pos++;
    }
  }
}

// ---------------------------------------------------------------------------
// Kernel 1: fp32 -> (bf16 hi, bf16 lo) split for gram rows [0,1366),
// fused with per-row sums.
__device__ __forceinline__ unsigned short f32_to_bf16_rne(float f) {
  unsigned u = __float_as_uint(f);
  unsigned r = (u + 0x7FFFu + ((u >> 16) & 1u)) >> 16;
  return (unsigned short)r;
}

__global__ __launch_bounds__(256) void conv_kernel(
    const float* __restrict__ x, unsigned short* __restrict__ xhi,
    unsigned short* __restrict__ xlo, float* __restrict__ sums)
{
  const int u = blockIdx.x;
  const int t = threadIdx.x;
  unsigned short* hrow = xhi + (size_t)u * HW_;
  unsigned short* lrow = xlo + (size_t)u * HW_;
  const float* row = x + (size_t)u * HW_;
  float s = 0.f;
#pragma unroll
  for (int i = 0; i < 4; i++) {
    const int col = i * 1024 + t * 4;
    const float4 v = *(const float4*)(row + col);
    s += v.x + v.y + v.z + v.w;
    ushort4 h, l;
    h.x = f32_to_bf16_rne(v.x);
    h.y = f32_to_bf16_rne(v.y);
    h.z = f32_to_bf16_rne(v.z);
    h.w = f32_to_bf16_rne(v.w);
    l.x = f32_to_bf16_rne(v.x - __uint_as_float((unsigned)h.x << 16));
    l.y = f32_to_bf16_rne(v.y - __uint_as_float((unsigned)h.y << 16));
    l.z = f32_to_bf16_rne(v.z - __uint_as_float((unsigned)h.z << 16));
    l.w = f32_to_bf16_rne(v.w - __uint_as_float((unsigned)h.w << 16));
    *(ushort4*)(hrow + col) = h;
    *(ushort4*)(lrow + col) = l;
  }
#pragma unroll
  for (int o = 32; o > 0; o >>= 1) s += __shfl_down(s, o);
  __shared__ float red[4];
  if ((t & 63) == 0) red[t >> 6] = s;
  __syncthreads();
  if (t == 0) sums[u] = red[0] + red[1] + red[2] + red[3];
}

// ---------------------------------------------------------------------------
// Kernel 2: Gram S[m][n] = x_row(m) . x_row(UK0+n) via bf16-split MFMA
// (Ahi*Bhi + Alo*Bhi + Ahi*Blo). 128x128 tile, 4 waves in 2x2 quadrants,
// full K-slice per block (no cross-wave reduction), direct global fragment
// loads, no LDS. Edge rows CLAMPED (m->682, k-row->1365): clamped lanes feed
// only outputs masked at the store, so xhi/xlo need just 1366 rows.
// 1-D grid, z = bid & 7: with round-robin block->XCD dispatch all 36 tiles
// of one K-slice share an XCD whose ~3.0 MB slice working set fits its 4 MB
// L2 (speed heuristic only; correctness never depends on it).
__global__ __launch_bounds__(256) void gram_mfma_kernel(
    const unsigned short* __restrict__ xhi, const unsigned short* __restrict__ xlo,
    float* __restrict__ P)
{
  const int bid  = blockIdx.x;
  const int z    = bid & 7;          // K-slice == (heuristically) XCD id
  const int tile = bid >> 3;         // 0..35
  const int m0 = (tile % NT) * 128;
  const int n0 = (tile / NT) * 128;

  const int t = threadIdx.x;
  const int wave = t >> 6;
  const int lane = t & 63;
  const int fr = lane & 15;
  const int fq = lane >> 4;
  const int wm = (wave >> 1) * 64;   // wave quadrant
  const int wn = (wave & 1) * 64;

  const int kbase = z * KSL + fq * 8;
  const unsigned short *pah[4], *pal[4], *pbh[4], *pbl[4];
#pragma unroll
  for (int i = 0; i < 4; i++) {
    const int ar = min(m0 + wm + fr + i * 16, NUQ - 1);
    const int br = min(UK0 + n0 + wn + fr + i * 16, NXU - 1);
    pah[i] = xhi + (size_t)ar * HW_ + kbase;
    pal[i] = xlo + (size_t)ar * HW_ + kbase;
    pbh[i] = xhi + (size_t)br * HW_ + kbase;
    pbl[i] = xlo + (size_t)br * HW_ + kbase;
  }

  floatx4 acc[4][4];
#pragma unroll
  for (int i = 0; i < 4; i++)
#pragma unroll
    for (int j = 0; j < 4; j++) acc[i][j] = (floatx4)(0.f);

  for (int kk = 0; kk < KSL; kk += 32) {
    short8 ah[4], al[4], bh[4], bl[4];
#pragma unroll
    for (int i = 0; i < 4; i++) {
      ah[i] = *(const short8*)(pah[i] + kk);
      al[i] = *(const short8*)(pal[i] + kk);
      bh[i] = *(const short8*)(pbh[i] + kk);
      bl[i] = *(const short8*)(pbl[i] + kk);
    }
#pragma unroll
    for (int mt = 0; mt < 4; mt++)
#pragma unroll
      for (int nt = 0; nt < 4; nt++) {
        acc[mt][nt] = __builtin_amdgcn_mfma_f32_16x16x32_bf16(ah[mt], bh[nt], acc[mt][nt], 0, 0, 0);
        acc[mt][nt] = __builtin_amdgcn_mfma_f32_16x16x32_bf16(al[mt], bh[nt], acc[mt][nt], 0, 0, 0);
        acc[mt][nt] = __builtin_amdgcn_mfma_f32_16x16x32_bf16(ah[mt], bl[nt], acc[mt][nt], 0, 0, 0);
      }
  }

  // direct epilogue: lane (fr,fq) holds C[row=fq*4+r][col=fr] per 16x16 tile.
  float* Pz = P + (size_t)z * NP1;
#pragma unroll
  for (int nt = 0; nt < 4; nt++) {
    const int gn = n0 + wn + nt * 16 + fr;
    if (gn >= NUK) continue;
#pragma unroll
    for (int mt = 0; mt < 4; mt++) {
      const floatx4 a = acc[mt][nt];
      const int gmb = m0 + wm + mt * 16 + fq * 4;
#pragma unroll
      for (int r = 0; r < 4; r++) {
        if (gmb + r < NUQ)
          Pz[(size_t)(gmb + r) * NUK + gn] = a[r];
      }
    }
  }
}

// ---------------------------------------------------------------------------
// Kernel 2b: S = sum of 8 P slices
__global__ __launch_bounds__(256) void gram_reduce_kernel(
    const float* __restrict__ P, float* __restrict__ S)
{
  const int idx = (blockIdx.x * 256 + threadIdx.x) * 4;
  if (idx < NP1) {
    float4 s = *(const float4*)(P + idx);
#pragma unroll
    for (int sl = 1; sl < SPLITK; sl++) {
      const float4 a = *(const float4*)(P + (size_t)sl * NP1 + idx);
      s.x += a.x; s.y += a.y; s.z += a.z; s.w += a.w;
    }
    *(float4*)(S + idx) = s;
  }
}

// ---------------------------------------------------------------------------
// block reductions
__device__ __forceinline__ float blockReduceMax(float v, float* red) {
#pragma unroll
  for (int o = 32; o > 0; o >>= 1) v = fmaxf(v, __shfl_down(v, o));
  if ((threadIdx.x & 63) == 0) red[threadIdx.x >> 6] = v;
  __syncthreads();
  v = fmaxf(fmaxf(red[0], red[1]), fmaxf(red[2], red[3]));
  __syncthreads();
  return v;
}
__device__ __forceinline__ float blockReduceSum(float v, float* red) {
#pragma unroll
  for (int o = 32; o > 0; o >>= 1) v += __shfl_down(v, o);
  if ((threadIdx.x & 63) == 0) red[threadIdx.x >> 6] = v;
  __syncthreads();
  v = red[0] + red[1] + red[2] + red[3];
  __syncthreads();
  return v;
}

// ---------------------------------------------------------------------------
// Kernel 3: softmax over reconstructed scores; emit bf16 coef (rows of CST,
// zero-padded) + cb; zero invalid rows of out.
__global__ __launch_bounds__(256) void softmax_kernel(
    const int* __restrict__ labels, const float* __restrict__ w,
    const float* __restrict__ bbias, const float* __restrict__ sums,
    const float* __restrict__ S, const int* __restrict__ grp_n,
    const int* __restrict__ members, const int* __restrict__ posArr,
    unsigned short* __restrict__ coefh, float* __restrict__ cb,
    float* __restrict__ out)
{
  const int i = blockIdx.x;
  const int t = threadIdx.x;
  const int g = labels[i];
  if (g < 0) {
    const float4 z = make_float4(0.f, 0.f, 0.f, 0.f);
    float4* orow = (float4*)(out + (size_t)i * HW_);
    for (int cidx = t; cidx < HW_ / 4; cidx += 256) orow[cidx] = z;
    return;
  }
  __shared__ float red[4];
  const int n   = grp_n[g];
  const int jq  = i % TC_;
  const int uqi = (i / TC_) * C_ + jq / 3;
  const float wq = w[jq], bq = bbias[jq];
  const float sq = sums[uqi];
  const float* Srow = S + (size_t)uqi * NUK;

  const int jj0 = t, jj1 = t + 256;
  float s0 = -FLT_MAX, s1 = -FLT_MAX;
  if (jj0 < n) {
    const int j = members[g * MAXG + jj0];
    const int rk = j + BC_;
    const int jk = rk % TC_;
    const int uk = (rk / TC_) * C_ + jk / 3;
    s0 = wq * w[jk] * Srow[uk - UK0] + (wq * bbias[jk]) * sq +
         (bq * w[jk]) * sums[uk] + (bq * bbias[jk]) * 4096.f;
  }
  if (jj1 < n) {
    const int j = members[g * MAXG + jj1];
    const int rk = j + BC_;
    const int jk = rk % TC_;
    const int uk = (rk / TC_) * C_ + jk / 3;
    s1 = wq * w[jk] * Srow[uk - UK0] + (wq * bbias[jk]) * sq +
         (bq * w[jk]) * sums[uk] + (bq * bbias[jk]) * 4096.f;
  }
  const float mx = blockReduceMax(fmaxf(s0, s1), red);
  const float e0 = (jj0 < n) ? expf(s0 - mx) : 0.f;
  const float e1 = (jj1 < n) ? expf(s1 - mx) : 0.f;
  const float tot = blockReduceSum(e0 + e1, red);
  const float inv = 1.f / tot;

  const int pos = posArr[i];
  unsigned short* crow = coefh + ((size_t)g * MCAP + pos) * CST;
  float lcb = 0.f;
  if (jj0 < n) {
    const int j = members[g * MAXG + jj0];
    const int jv = (j + 2 * BC_) % TC_;
    const float wgt = e0 * inv;
    if (pos < MCAP && jj0 < CST) crow[jj0] = f32_to_bf16_rne(wgt * w[jv]);
    lcb += wgt * bbias[jv];
  } else if (pos < MCAP && jj0 < CST) {
    crow[jj0] = 0;                 // zero-pad K columns n..CST-1
  }
  if (jj1 < n) {
    const int j = members[g * MAXG + jj1];
    const int jv = (j + 2 * BC_) % TC_;
    const float wgt = e1 * inv;
    lcb += wgt * bbias[jv];        // jj1 >= 256 > CST: never stored in coefh
  }
  const float cbi = blockReduceSum(lcb, red);
  if (t == 0) cb[i] = cbi;
}

// ---------------------------------------------------------------------------
// Kernel 4: out rows of group g = coef[g] (n x K) @ B^T where B[col][k] =
// bf16(x[uv_k][col]). Block = (g, 64-col chunk). B-tile gathered from fp32 x
// (converted on the fly) into LDS once, reused by all m-tiles; A fragments
// direct from global (K-contiguous).
__global__ __launch_bounds__(256) void out_mfma_kernel(
    const float* __restrict__ x, const unsigned short* __restrict__ coefh,
    const float* __restrict__ cb, const int* __restrict__ grp_n,
    const int* __restrict__ members, float* __restrict__ out)
{
  const int g  = blockIdx.x;
  const int c0 = blockIdx.y * 64;
  const int n  = min(grp_n[g], MCAP);
  if (n == 0) return;
  const int Kceil = (n + 31) & ~31;
  const int t = threadIdx.x;
  const int wave = t >> 6;
  const int lane = t & 63;
  const int fr = lane & 15;
  const int fq = lane >> 4;

  __shared__ unsigned short Bt[64][BKP];
  __shared__ int   mem[MCAP];
  __shared__ float cbs[MCAP];

  if (t < n) {
    const int j = members[g * MAXG + t];
    mem[t] = j;
    cbs[t] = cb[j];
  }
  __syncthreads();

  // gather B tile: Bt[col][k] = bf16(x[uv_k][c0 + col])
  for (int kk = wave; kk < Kceil; kk += 4) {
    unsigned short v = 0;
    if (kk < n) {
      const int j = mem[kk];
      const int rv = j + 2 * BC_;
      const int uv = (rv / TC_) * C_ + (rv % TC_) / 3;
      v = f32_to_bf16_rne(x[(size_t)uv * HW_ + c0 + lane]);
    }
    Bt[lane][kk] = v;
  }
  __syncthreads();

  const int colw = wave * 16 + fr;

  for (int m0 = 0; m0 < n; m0 += 32) {
    floatx4 acc0 = (floatx4)(0.f), acc1 = (floatx4)(0.f);
    const unsigned short* pa0 = coefh + ((size_t)g * MCAP + m0 + fr) * CST + fq * 8;
    const unsigned short* pa1 = pa0 + 16 * CST;
    for (int k = 0; k < Kceil; k += 32) {
      const short8 a0 = *(const short8*)(pa0 + k);
      const short8 a1 = *(const short8*)(pa1 + k);
      const short8 b  = *(const short8*)&Bt[colw][fq * 8 + k];
      acc0 = __builtin_amdgcn_mfma_f32_16x16x32_bf16(a0, b, acc0, 0, 0, 0);
      acc1 = __builtin_amdgcn_mfma_f32_16x16x32_bf16(a1, b, acc1, 0, 0, 0);
    }
#pragma unroll
    for (int r = 0; r < 4; r++) {
      int m = m0 + fq * 4 + r;
      if (m < n) out[(size_t)mem[m] * HW_ + c0 + colw] = acc0[r] + cbs[m];
      m += 16;
      if (m < n) out[(size_t)mem[m] * HW_ + c0 + colw] = acc1[r] + cbs[m];
    }
  }
}

// ---------------------------------------------------------------------------
extern "C" void kernel_launch(void* const* d_in, const int* in_sizes, int n_in,
                              void* d_out, int out_size, void* d_ws, size_t ws_size,
                              hipStream_t stream)
{
  const float* x      = (const float*)d_in[0];
  const int*   labels = (const int*)d_in[1];
  const float* w      = (const float*)d_in[2];
  const float* bb     = (const float*)d_in[3];
  float* out = (float*)d_out;

  // workspace carve: ~40.4 MB total (< proven-working 41.0 MB envelope)
  char* wsb = (char*)d_ws;
  size_t off = 0;
  auto carve = [&](size_t bytes) -> void* {
    off = (off + 255) & ~(size_t)255;
    void* p = wsb + off;
    off += bytes;
    return p;
  };
  float* sums    = (float*)carve(NXU * sizeof(float));
  float* S       = (float*)carve((size_t)NP1 * sizeof(float));
  float* P       = (float*)carve((size_t)SPLITK * NP1 * sizeof(float));
  int*   grp_n   = (int*)carve(NG_ * sizeof(int));
  int*   members = (int*)carve((size_t)NG_ * MAXG * sizeof(int));
  int*   posArr  = (int*)carve(BC_ * sizeof(int));
  unsigned short* coefh = (unsigned short*)carve((size_t)NG_ * MCAP * CST * sizeof(unsigned short));
  float* cb      = (float*)carve(BC_ * sizeof(float));
  unsigned short* xhi = (unsigned short*)carve((size_t)NXU * HW_ * sizeof(unsigned short));
  unsigned short* xlo = (unsigned short*)carve((size_t)NXU * HW_ * sizeof(unsigned short));

  conv_kernel<<<NXU, 256, 0, stream>>>(x, xhi, xlo, sums);
  group_build_kernel<<<NG_, 256, 0, stream>>>(labels, grp_n, members, posArr);
  gram_mfma_kernel<<<NTILES * SPLITK, 256, 0, stream>>>(xhi, xlo, P);
  gram_reduce_kernel<<<(NP1 / 4 + 255) / 256, 256, 0, stream>>>(P, S);
  softmax_kernel<<<BC_, 256, 0, stream>>>(labels, w, bb, sums, S, grp_n,
                                          members, posArr, coefh, cb, out);
  out_mfma_kernel<<<dim3(NG_, HW_ / 64), 256, 0, stream>>>(
      x, coefh, cb, grp_n, members, out);
}

// Round 9
// 172.954 us; speedup vs baseline: 1.1088x; 1.1088x over previous
//
#include <hip/hip_runtime.h>
#include <cfloat>

// Problem constants (fixed by the reference)
#define B_   8
#define C_   256
#define HW_  4096
#define BC_  2048      // B*C  (q/k/v row count)
#define TC_  768       // 3*C
#define NG_  16        // valid labels 0..15 (-1 invalid)
#define MAXG 320       // members[] capacity per group
#define UK0  682       // first x-row index used by k
#define NUQ  683       // x rows used by q: u in [0,682]
#define NUK  684       // x rows used by k: u in [682,1365]
#define NXU  1366      // x rows used by gram (q+k); xhi/xlo row count

// Gram MFMA: 64x64 tiles, 11x11 grid, 4 waves split K, split-K=8 XCD-pinned
#define SPLITK 8
#define NT     11                   // ceil(684/64)
#define NTILES (NT * NT)            // 121
#define KSL    (HW_ / SPLITK)       // 512: K span per slice (block)
#define WKC    (KSL / 4)            // 128: K span per wave
#define NP1    (NUQ * NUK)          // one partial buffer (467172, /4 exact)

// Out GEMM / coef
#define MCAP  192      // supported group size (n ~ 120 +- 11; 192 is ~6.7 sigma)
#define CST   192      // coefh row stride (ushorts)
#define BKP   200      // Bt LDS row stride in ushorts (16B-aligned rows)

typedef __attribute__((ext_vector_type(8))) short short8;
typedef __attribute__((ext_vector_type(4))) float floatx4;

// ---------------------------------------------------------------------------
// Kernel 0: build label-group membership. One block per group; deterministic
// ordered build via block-wide scan (no atomics).
__global__ __launch_bounds__(256) void group_build_kernel(
    const int* __restrict__ labels, int* __restrict__ grp_n,
    int* __restrict__ members, int* __restrict__ posArr)
{
  __shared__ int lab[BC_];
  __shared__ int cnts[256];
  const int g = blockIdx.x;
  const int t = threadIdx.x;
  for (int idx = t; idx < BC_; idx += 256) lab[idx] = labels[idx];
  __syncthreads();

  const int base = t * 8;
  int cnt = 0;
#pragma unroll
  for (int k = 0; k < 8; k++) cnt += (lab[base + k] == g) ? 1 : 0;
  cnts[t] = cnt;
  for (int off = 1; off < 256; off <<= 1) {
    __syncthreads();
    const int v = (t >= off) ? cnts[t - off] : 0;
    __syncthreads();
    cnts[t] += v;
  }
  __syncthreads();
  int pos = cnts[t] - cnt;
  if (t == 255) grp_n[g] = cnts[255] < MAXG ? cnts[255] : MAXG;
#pragma unroll
  for (int k = 0; k < 8; k++) {
    const int i = base + k;
    if (lab[i] == g) {
      if (pos < MAXG) { members[g * MAXG + pos] = i; posArr[i] = pos; }
      pos++;
    }
  }
}

// ---------------------------------------------------------------------------
// Kernel 1: fp32 -> (bf16 hi, bf16 lo) split for gram rows [0,1366),
// fused with per-row sums.
__device__ __forceinline__ unsigned short f32_to_bf16_rne(float f) {
  unsigned u = __float_as_uint(f);
  unsigned r = (u + 0x7FFFu + ((u >> 16) & 1u)) >> 16;
  return (unsigned short)r;
}

__global__ __launch_bounds__(256) void conv_kernel(
    const float* __restrict__ x, unsigned short* __restrict__ xhi,
    unsigned short* __restrict__ xlo, float* __restrict__ sums)
{
  const int u = blockIdx.x;
  const int t = threadIdx.x;
  unsigned short* hrow = xhi + (size_t)u * HW_;
  unsigned short* lrow = xlo + (size_t)u * HW_;
  const float* row = x + (size_t)u * HW_;
  float s = 0.f;
#pragma unroll
  for (int i = 0; i < 4; i++) {
    const int col = i * 1024 + t * 4;
    const float4 v = *(const float4*)(row + col);
    s += v.x + v.y + v.z + v.w;
    ushort4 h, l;
    h.x = f32_to_bf16_rne(v.x);
    h.y = f32_to_bf16_rne(v.y);
    h.z = f32_to_bf16_rne(v.z);
    h.w = f32_to_bf16_rne(v.w);
    l.x = f32_to_bf16_rne(v.x - __uint_as_float((unsigned)h.x << 16));
    l.y = f32_to_bf16_rne(v.y - __uint_as_float((unsigned)h.y << 16));
    l.z = f32_to_bf16_rne(v.z - __uint_as_float((unsigned)h.z << 16));
    l.w = f32_to_bf16_rne(v.w - __uint_as_float((unsigned)h.w << 16));
    *(ushort4*)(hrow + col) = h;
    *(ushort4*)(lrow + col) = l;
  }
#pragma unroll
  for (int o = 32; o > 0; o >>= 1) s += __shfl_down(s, o);
  __shared__ float red[4];
  if ((t & 63) == 0) red[t >> 6] = s;
  __syncthreads();
  if (t == 0) sums[u] = red[0] + red[1] + red[2] + red[3];
}

// ---------------------------------------------------------------------------
// Kernel 2: Gram S[m][n] = x_row(m) . x_row(UK0+n) via bf16-split MFMA
// (Ahi*Bhi + Alo*Bhi + Ahi*Blo). 64x64 tile per block; the 4 waves split the
// block's 512-wide K slice (128 each) for TLP, then LDS-fold. Direct global
// fragment loads, no LDS in K-loop, no atomics. Edge rows CLAMPED (m->682,
// k-row->1365): clamped lanes feed only store-masked outputs.
// 1-D grid, z = bid & 7: with round-robin block->XCD dispatch all 121 tiles
// of one K-slice share an XCD whose ~3.0 MB working set fits its 4 MB L2
// (speed heuristic only; R8 measured FETCH 174->11 MB from this pinning).
__global__ __launch_bounds__(256) void gram_mfma_kernel(
    const unsigned short* __restrict__ xhi, const unsigned short* __restrict__ xlo,
    float* __restrict__ P)
{
  const int bid  = blockIdx.x;
  const int z    = bid & 7;          // K-slice == (heuristically) XCD id
  const int tile = bid >> 3;         // 0..120
  const int m0 = (tile % NT) * 64;
  const int n0 = (tile / NT) * 64;

  const int t = threadIdx.x;
  const int wave = t >> 6;
  const int lane = t & 63;
  const int fr = lane & 15;
  const int fq = lane >> 4;

  const int kbase = z * KSL + wave * WKC + fq * 8;
  const unsigned short *pah[4], *pal[4], *pbh[4], *pbl[4];
#pragma unroll
  for (int i = 0; i < 4; i++) {
    const int ar = min(m0 + fr + i * 16, NUQ - 1);
    const int br = min(UK0 + n0 + fr + i * 16, NXU - 1);
    pah[i] = xhi + (size_t)ar * HW_ + kbase;
    pal[i] = xlo + (size_t)ar * HW_ + kbase;
    pbh[i] = xhi + (size_t)br * HW_ + kbase;
    pbl[i] = xlo + (size_t)br * HW_ + kbase;
  }

  floatx4 acc[4][4];
#pragma unroll
  for (int i = 0; i < 4; i++)
#pragma unroll
    for (int j = 0; j < 4; j++) acc[i][j] = (floatx4)(0.f);

  for (int kk = 0; kk < WKC; kk += 32) {
    short8 ah[4], al[4], bh[4], bl[4];
#pragma unroll
    for (int i = 0; i < 4; i++) {
      ah[i] = *(const short8*)(pah[i] + kk);
      al[i] = *(const short8*)(pal[i] + kk);
      bh[i] = *(const short8*)(pbh[i] + kk);
      bl[i] = *(const short8*)(pbl[i] + kk);
    }
#pragma unroll
    for (int mt = 0; mt < 4; mt++)
#pragma unroll
      for (int nt = 0; nt < 4; nt++) {
        acc[mt][nt] = __builtin_amdgcn_mfma_f32_16x16x32_bf16(ah[mt], bh[nt], acc[mt][nt], 0, 0, 0);
        acc[mt][nt] = __builtin_amdgcn_mfma_f32_16x16x32_bf16(al[mt], bh[nt], acc[mt][nt], 0, 0, 0);
        acc[mt][nt] = __builtin_amdgcn_mfma_f32_16x16x32_bf16(ah[mt], bl[nt], acc[mt][nt], 0, 0, 0);
      }
  }

  // cross-wave fold in LDS (2 regions), then plain float4 stores to P[z].
  __shared__ float R[2][64][68];
  float* R0 = &R[0][0][0];
  float* R1 = &R[1][0][0];
  if (wave == 0 || wave == 2) {
    float* Rw = (wave == 0) ? R0 : R1;
#pragma unroll
    for (int mt = 0; mt < 4; mt++)
#pragma unroll
      for (int nt = 0; nt < 4; nt++)
#pragma unroll
        for (int r = 0; r < 4; r++)
          Rw[(mt * 16 + fq * 4 + r) * 68 + nt * 16 + fr] = acc[mt][nt][r];
  }
  __syncthreads();
  if (wave == 1 || wave == 3) {
    float* Rw = (wave == 1) ? R0 : R1;
#pragma unroll
    for (int mt = 0; mt < 4; mt++)
#pragma unroll
      for (int nt = 0; nt < 4; nt++)
#pragma unroll
        for (int r = 0; r < 4; r++)
          Rw[(mt * 16 + fq * 4 + r) * 68 + nt * 16 + fr] += acc[mt][nt][r];
  }
  __syncthreads();
  const int em = t >> 2;           // 0..63
  const int en = (t & 3) * 16;     // 0,16,32,48
  const int gm = m0 + em;
  if (gm < NUQ) {
    float* dst = P + (size_t)z * NP1 + (size_t)gm * NUK + n0;
#pragma unroll
    for (int i4 = 0; i4 < 4; i4++) {
      const int n = en + i4 * 4;
      if (n0 + n < NUK) {          // NUK % 4 == 0: float4-granular guard exact
        float4 v;
        v.x = R0[em * 68 + n + 0] + R1[em * 68 + n + 0];
        v.y = R0[em * 68 + n + 1] + R1[em * 68 + n + 1];
        v.z = R0[em * 68 + n + 2] + R1[em * 68 + n + 2];
        v.w = R0[em * 68 + n + 3] + R1[em * 68 + n + 3];
        *(float4*)(dst + n) = v;
      }
    }
  }
}

// ---------------------------------------------------------------------------
// Kernel 2b: S = sum of 8 P slices
__global__ __launch_bounds__(256) void gram_reduce_kernel(
    const float* __restrict__ P, float* __restrict__ S)
{
  const int idx = (blockIdx.x * 256 + threadIdx.x) * 4;
  if (idx < NP1) {
    float4 s = *(const float4*)(P + idx);
#pragma unroll
    for (int sl = 1; sl < SPLITK; sl++) {
      const float4 a = *(const float4*)(P + (size_t)sl * NP1 + idx);
      s.x += a.x; s.y += a.y; s.z += a.z; s.w += a.w;
    }
    *(float4*)(S + idx) = s;
  }
}

// ---------------------------------------------------------------------------
// block reductions
__device__ __forceinline__ float blockReduceMax(float v, float* red) {
#pragma unroll
  for (int o = 32; o > 0; o >>= 1) v = fmaxf(v, __shfl_down(v, o));
  if ((threadIdx.x & 63) == 0) red[threadIdx.x >> 6] = v;
  __syncthreads();
  v = fmaxf(fmaxf(red[0], red[1]), fmaxf(red[2], red[3]));
  __syncthreads();
  return v;
}
__device__ __forceinline__ float blockReduceSum(float v, float* red) {
#pragma unroll
  for (int o = 32; o > 0; o >>= 1) v += __shfl_down(v, o);
  if ((threadIdx.x & 63) == 0) red[threadIdx.x >> 6] = v;
  __syncthreads();
  v = red[0] + red[1] + red[2] + red[3];
  __syncthreads();
  return v;
}

// ---------------------------------------------------------------------------
// Kernel 3: softmax over reconstructed scores; emit bf16 coef (rows of CST,
// zero-padded) + cb; zero invalid rows of out.
__global__ __launch_bounds__(256) void softmax_kernel(
    const int* __restrict__ labels, const float* __restrict__ w,
    const float* __restrict__ bbias, const float* __restrict__ sums,
    const float* __restrict__ S, const int* __restrict__ grp_n,
    const int* __restrict__ members, const int* __restrict__ posArr,
    unsigned short* __restrict__ coefh, float* __restrict__ cb,
    float* __restrict__ out)
{
  const int i = blockIdx.x;
  const int t = threadIdx.x;
  const int g = labels[i];
  if (g < 0) {
    const float4 z = make_float4(0.f, 0.f, 0.f, 0.f);
    float4* orow = (float4*)(out + (size_t)i * HW_);
    for (int cidx = t; cidx < HW_ / 4; cidx += 256) orow[cidx] = z;
    return;
  }
  __shared__ float red[4];
  const int n   = grp_n[g];
  const int jq  = i % TC_;
  const int uqi = (i / TC_) * C_ + jq / 3;
  const float wq = w[jq], bq = bbias[jq];
  const float sq = sums[uqi];
  const float* Srow = S + (size_t)uqi * NUK;

  const int jj0 = t, jj1 = t + 256;
  float s0 = -FLT_MAX, s1 = -FLT_MAX;
  if (jj0 < n) {
    const int j = members[g * MAXG + jj0];
    const int rk = j + BC_;
    const int jk = rk % TC_;
    const int uk = (rk / TC_) * C_ + jk / 3;
    s0 = wq * w[jk] * Srow[uk - UK0] + (wq * bbias[jk]) * sq +
         (bq * w[jk]) * sums[uk] + (bq * bbias[jk]) * 4096.f;
  }
  if (jj1 < n) {
    const int j = members[g * MAXG + jj1];
    const int rk = j + BC_;
    const int jk = rk % TC_;
    const int uk = (rk / TC_) * C_ + jk / 3;
    s1 = wq * w[jk] * Srow[uk - UK0] + (wq * bbias[jk]) * sq +
         (bq * w[jk]) * sums[uk] + (bq * bbias[jk]) * 4096.f;
  }
  const float mx = blockReduceMax(fmaxf(s0, s1), red);
  const float e0 = (jj0 < n) ? expf(s0 - mx) : 0.f;
  const float e1 = (jj1 < n) ? expf(s1 - mx) : 0.f;
  const float tot = blockReduceSum(e0 + e1, red);
  const float inv = 1.f / tot;

  const int pos = posArr[i];
  unsigned short* crow = coefh + ((size_t)g * MCAP + pos) * CST;
  float lcb = 0.f;
  if (jj0 < n) {
    const int j = members[g * MAXG + jj0];
    const int jv = (j + 2 * BC_) % TC_;
    const float wgt = e0 * inv;
    if (pos < MCAP && jj0 < CST) crow[jj0] = f32_to_bf16_rne(wgt * w[jv]);
    lcb += wgt * bbias[jv];
  } else if (pos < MCAP && jj0 < CST) {
    crow[jj0] = 0;                 // zero-pad K columns n..CST-1
  }
  if (jj1 < n) {
    const int j = members[g * MAXG + jj1];
    const int jv = (j + 2 * BC_) % TC_;
    const float wgt = e1 * inv;
    lcb += wgt * bbias[jv];        // jj1 >= 256 > CST: never stored in coefh
  }
  const float cbi = blockReduceSum(lcb, red);
  if (t == 0) cb[i] = cbi;
}

// ---------------------------------------------------------------------------
// Kernel 4: out rows of group g = coef[g] (n x K) @ B^T where B[col][k] =
// bf16(x[uv_k][col]). Block = (g, 64-col chunk). B-tile gathered from fp32 x
// (converted on the fly) into LDS once, reused by all m-tiles; A fragments
// direct from global (K-contiguous).
__global__ __launch_bounds__(256) void out_mfma_kernel(
    const float* __restrict__ x, const unsigned short* __restrict__ coefh,
    const float* __restrict__ cb, const int* __restrict__ grp_n,
    const int* __restrict__ members, float* __restrict__ out)
{
  const int g  = blockIdx.x;
  const int c0 = blockIdx.y * 64;
  const int n  = min(grp_n[g], MCAP);
  if (n == 0) return;
  const int Kceil = (n + 31) & ~31;
  const int t = threadIdx.x;
  const int wave = t >> 6;
  const int lane = t & 63;
  const int fr = lane & 15;
  const int fq = lane >> 4;

  __shared__ unsigned short Bt[64][BKP];
  __shared__ int   mem[MCAP];
  __shared__ float cbs[MCAP];

  if (t < n) {
    const int j = members[g * MAXG + t];
    mem[t] = j;
    cbs[t] = cb[j];
  }
  __syncthreads();

  // gather B tile: Bt[col][k] = bf16(x[uv_k][c0 + col])
  for (int kk = wave; kk < Kceil; kk += 4) {
    unsigned short v = 0;
    if (kk < n) {
      const int j = mem[kk];
      const int rv = j + 2 * BC_;
      const int uv = (rv / TC_) * C_ + (rv % TC_) / 3;
      v = f32_to_bf16_rne(x[(size_t)uv * HW_ + c0 + lane]);
    }
    Bt[lane][kk] = v;
  }
  __syncthreads();

  const int colw = wave * 16 + fr;

  for (int m0 = 0; m0 < n; m0 += 32) {
    floatx4 acc0 = (floatx4)(0.f), acc1 = (floatx4)(0.f);
    const unsigned short* pa0 = coefh + ((size_t)g * MCAP + m0 + fr) * CST + fq * 8;
    const unsigned short* pa1 = pa0 + 16 * CST;
    for (int k = 0; k < Kceil; k += 32) {
      const short8 a0 = *(const short8*)(pa0 + k);
      const short8 a1 = *(const short8*)(pa1 + k);
      const short8 b  = *(const short8*)&Bt[colw][fq * 8 + k];
      acc0 = __builtin_amdgcn_mfma_f32_16x16x32_bf16(a0, b, acc0, 0, 0, 0);
      acc1 = __builtin_amdgcn_mfma_f32_16x16x32_bf16(a1, b, acc1, 0, 0, 0);
    }
#pragma unroll
    for (int r = 0; r < 4; r++) {
      int m = m0 + fq * 4 + r;
      if (m < n) out[(size_t)mem[m] * HW_ + c0 + colw] = acc0[r] + cbs[m];
      m += 16;
      if (m < n) out[(size_t)mem[m] * HW_ + c0 + colw] = acc1[r] + cbs[m];
    }
  }
}

// ---------------------------------------------------------------------------
extern "C" void kernel_launch(void* const* d_in, const int* in_sizes, int n_in,
                              void* d_out, int out_size, void* d_ws, size_t ws_size,
                              hipStream_t stream)
{
  const float* x      = (const float*)d_in[0];
  const int*   labels = (const int*)d_in[1];
  const float* w      = (const float*)d_in[2];
  const float* bb     = (const float*)d_in[3];
  float* out = (float*)d_out;

  // workspace carve: ~40.4 MB total (< proven-working 41.0 MB envelope)
  char* wsb = (char*)d_ws;
  size_t off = 0;
  auto carve = [&](size_t bytes) -> void* {
    off = (off + 255) & ~(size_t)255;
    void* p = wsb + off;
    off += bytes;
    return p;
  };
  float* sums    = (float*)carve(NXU * sizeof(float));
  float* S       = (float*)carve((size_t)NP1 * sizeof(float));
  float* P       = (float*)carve((size_t)SPLITK * NP1 * sizeof(float));
  int*   grp_n   = (int*)carve(NG_ * sizeof(int));
  int*   members = (int*)carve((size_t)NG_ * MAXG * sizeof(int));
  int*   posArr  = (int*)carve(BC_ * sizeof(int));
  unsigned short* coefh = (unsigned short*)carve((size_t)NG_ * MCAP * CST * sizeof(unsigned short));
  float* cb      = (float*)carve(BC_ * sizeof(float));
  unsigned short* xhi = (unsigned short*)carve((size_t)NXU * HW_ * sizeof(unsigned short));
  unsigned short* xlo = (unsigned short*)carve((size_t)NXU * HW_ * sizeof(unsigned short));

  conv_kernel<<<NXU, 256, 0, stream>>>(x, xhi, xlo, sums);
  group_build_kernel<<<NG_, 256, 0, stream>>>(labels, grp_n, members, posArr);
  gram_mfma_kernel<<<NTILES * SPLITK, 256, 0, stream>>>(xhi, xlo, P);
  gram_reduce_kernel<<<(NP1 / 4 + 255) / 256, 256, 0, stream>>>(P, S);
  softmax_kernel<<<BC_, 256, 0, stream>>>(labels, w, bb, sums, S, grp_n,
                                          members, posArr, coefh, cb, out);
  out_mfma_kernel<<<dim3(NG_, HW_ / 64), 256, 0, stream>>>(
      x, coefh, cb, grp_n, members, out);
}

// Round 10
// 165.798 us; speedup vs baseline: 1.1567x; 1.0432x over previous
//
#include <hip/hip_runtime.h>
#include <cfloat>

// Problem constants (fixed by the reference)
#define B_   8
#define C_   256
#define HW_  4096
#define BC_  2048      // B*C  (q/k/v row count)
#define TC_  768       // 3*C
#define NG_  16        // valid labels 0..15 (-1 invalid)
#define MAXG 320       // members[] capacity per group
#define UK0  682       // first x-row index used by k
#define NUQ  683       // x rows used by q: u in [0,682]
#define NUK  684       // x rows used by k: u in [682,1365]
#define NXU  1366      // x rows used by gram (q+k); xhi/xlo row count

// Gram MFMA: 64x64 tiles, 11x11 grid, 4 waves split K, split-K=8 XCD-pinned
#define SPLITK 8
#define NT     11                   // ceil(684/64)
#define NTILES (NT * NT)            // 121
#define KSL    (HW_ / SPLITK)       // 512: K span per slice (block)
#define WKC    (KSL / 4)            // 128: K span per wave
#define NP1    (NUQ * NUK)          // one partial buffer (467172, /4 exact)

// Out GEMM / coef
#define MCAP  192      // supported group size (n ~ 120 +- 11; 192 is ~6.7 sigma)
#define CST   192      // coefh row stride (ushorts)
#define BKP   216      // Bt LDS row stride in ushorts (432 B = 27*16: b128-aligned)

typedef __attribute__((ext_vector_type(8))) short short8;
typedef __attribute__((ext_vector_type(4))) float floatx4;

// ---------------------------------------------------------------------------
// Kernel 0: build label-group membership. One block per group; deterministic
// ordered build via block-wide scan (no atomics).
__global__ __launch_bounds__(256) void group_build_kernel(
    const int* __restrict__ labels, int* __restrict__ grp_n,
    int* __restrict__ members, int* __restrict__ posArr)
{
  __shared__ int lab[BC_];
  __shared__ int cnts[256];
  const int g = blockIdx.x;
  const int t = threadIdx.x;
  for (int idx = t; idx < BC_; idx += 256) lab[idx] = labels[idx];
  __syncthreads();

  const int base = t * 8;
  int cnt = 0;
#pragma unroll
  for (int k = 0; k < 8; k++) cnt += (lab[base + k] == g) ? 1 : 0;
  cnts[t] = cnt;
  for (int off = 1; off < 256; off <<= 1) {
    __syncthreads();
    const int v = (t >= off) ? cnts[t - off] : 0;
    __syncthreads();
    cnts[t] += v;
  }
  __syncthreads();
  int pos = cnts[t] - cnt;
  if (t == 255) grp_n[g] = cnts[255] < MAXG ? cnts[255] : MAXG;
#pragma unroll
  for (int k = 0; k < 8; k++) {
    const int i = base + k;
    if (lab[i] == g) {
      if (pos < MAXG) { members[g * MAXG + pos] = i; posArr[i] = pos; }
      pos++;
    }
  }
}

// ---------------------------------------------------------------------------
// Kernel 1: fp32 -> (bf16 hi, bf16 lo) split for gram rows [0,1366),
// fused with per-row sums.
__device__ __forceinline__ unsigned short f32_to_bf16_rne(float f) {
  unsigned u = __float_as_uint(f);
  unsigned r = (u + 0x7FFFu + ((u >> 16) & 1u)) >> 16;
  return (unsigned short)r;
}

__global__ __launch_bounds__(256) void conv_kernel(
    const float* __restrict__ x, unsigned short* __restrict__ xhi,
    unsigned short* __restrict__ xlo, float* __restrict__ sums)
{
  const int u = blockIdx.x;
  const int t = threadIdx.x;
  unsigned short* hrow = xhi + (size_t)u * HW_;
  unsigned short* lrow = xlo + (size_t)u * HW_;
  const float* row = x + (size_t)u * HW_;
  float s = 0.f;
#pragma unroll
  for (int i = 0; i < 4; i++) {
    const int col = i * 1024 + t * 4;
    const float4 v = *(const float4*)(row + col);
    s += v.x + v.y + v.z + v.w;
    ushort4 h, l;
    h.x = f32_to_bf16_rne(v.x);
    h.y = f32_to_bf16_rne(v.y);
    h.z = f32_to_bf16_rne(v.z);
    h.w = f32_to_bf16_rne(v.w);
    l.x = f32_to_bf16_rne(v.x - __uint_as_float((unsigned)h.x << 16));
    l.y = f32_to_bf16_rne(v.y - __uint_as_float((unsigned)h.y << 16));
    l.z = f32_to_bf16_rne(v.z - __uint_as_float((unsigned)h.z << 16));
    l.w = f32_to_bf16_rne(v.w - __uint_as_float((unsigned)h.w << 16));
    *(ushort4*)(hrow + col) = h;
    *(ushort4*)(lrow + col) = l;
  }
#pragma unroll
  for (int o = 32; o > 0; o >>= 1) s += __shfl_down(s, o);
  __shared__ float red[4];
  if ((t & 63) == 0) red[t >> 6] = s;
  __syncthreads();
  if (t == 0) sums[u] = red[0] + red[1] + red[2] + red[3];
}

// ---------------------------------------------------------------------------
// Kernel 2: Gram S[m][n] = x_row(m) . x_row(UK0+n) via bf16-split MFMA
// (Ahi*Bhi + Alo*Bhi + Ahi*Blo). 64x64 tile per block; the 4 waves split the
// block's 512-wide K slice (128 each) for TLP, then LDS-fold. Direct global
// fragment loads, no LDS in K-loop, no atomics. Edge rows CLAMPED (m->682,
// k-row->1365): clamped lanes feed only store-masked outputs.
// 1-D grid, z = bid & 7: with round-robin block->XCD dispatch all 121 tiles
// of one K-slice share an XCD whose ~3.0 MB working set fits its 4 MB L2
// (speed heuristic only; R8 measured FETCH 174->11 MB from this pinning).
__global__ __launch_bounds__(256) void gram_mfma_kernel(
    const unsigned short* __restrict__ xhi, const unsigned short* __restrict__ xlo,
    float* __restrict__ P)
{
  const int bid  = blockIdx.x;
  const int z    = bid & 7;          // K-slice == (heuristically) XCD id
  const int tile = bid >> 3;         // 0..120
  const int m0 = (tile % NT) * 64;
  const int n0 = (tile / NT) * 64;

  const int t = threadIdx.x;
  const int wave = t >> 6;
  const int lane = t & 63;
  const int fr = lane & 15;
  const int fq = lane >> 4;

  const int kbase = z * KSL + wave * WKC + fq * 8;
  const unsigned short *pah[4], *pal[4], *pbh[4], *pbl[4];
#pragma unroll
  for (int i = 0; i < 4; i++) {
    const int ar = min(m0 + fr + i * 16, NUQ - 1);
    const int br = min(UK0 + n0 + fr + i * 16, NXU - 1);
    pah[i] = xhi + (size_t)ar * HW_ + kbase;
    pal[i] = xlo + (size_t)ar * HW_ + kbase;
    pbh[i] = xhi + (size_t)br * HW_ + kbase;
    pbl[i] = xlo + (size_t)br * HW_ + kbase;
  }

  floatx4 acc[4][4];
#pragma unroll
  for (int i = 0; i < 4; i++)
#pragma unroll
    for (int j = 0; j < 4; j++) acc[i][j] = (floatx4)(0.f);

  for (int kk = 0; kk < WKC; kk += 32) {
    short8 ah[4], al[4], bh[4], bl[4];
#pragma unroll
    for (int i = 0; i < 4; i++) {
      ah[i] = *(const short8*)(pah[i] + kk);
      al[i] = *(const short8*)(pal[i] + kk);
      bh[i] = *(const short8*)(pbh[i] + kk);
      bl[i] = *(const short8*)(pbl[i] + kk);
    }
#pragma unroll
    for (int mt = 0; mt < 4; mt++)
#pragma unroll
      for (int nt = 0; nt < 4; nt++) {
        acc[mt][nt] = __builtin_amdgcn_mfma_f32_16x16x32_bf16(ah[mt], bh[nt], acc[mt][nt], 0, 0, 0);
        acc[mt][nt] = __builtin_amdgcn_mfma_f32_16x16x32_bf16(al[mt], bh[nt], acc[mt][nt], 0, 0, 0);
        acc[mt][nt] = __builtin_amdgcn_mfma_f32_16x16x32_bf16(ah[mt], bl[nt], acc[mt][nt], 0, 0, 0);
      }
  }

  // cross-wave fold in LDS (2 regions), then plain float4 stores to P[z].
  __shared__ float R[2][64][68];
  float* R0 = &R[0][0][0];
  float* R1 = &R[1][0][0];
  if (wave == 0 || wave == 2) {
    float* Rw = (wave == 0) ? R0 : R1;
#pragma unroll
    for (int mt = 0; mt < 4; mt++)
#pragma unroll
      for (int nt = 0; nt < 4; nt++)
#pragma unroll
        for (int r = 0; r < 4; r++)
          Rw[(mt * 16 + fq * 4 + r) * 68 + nt * 16 + fr] = acc[mt][nt][r];
  }
  __syncthreads();
  if (wave == 1 || wave == 3) {
    float* Rw = (wave == 1) ? R0 : R1;
#pragma unroll
    for (int mt = 0; mt < 4; mt++)
#pragma unroll
      for (int nt = 0; nt < 4; nt++)
#pragma unroll
        for (int r = 0; r < 4; r++)
          Rw[(mt * 16 + fq * 4 + r) * 68 + nt * 16 + fr] += acc[mt][nt][r];
  }
  __syncthreads();
  const int em = t >> 2;           // 0..63
  const int en = (t & 3) * 16;     // 0,16,32,48
  const int gm = m0 + em;
  if (gm < NUQ) {
    float* dst = P + (size_t)z * NP1 + (size_t)gm * NUK + n0;
#pragma unroll
    for (int i4 = 0; i4 < 4; i4++) {
      const int n = en + i4 * 4;
      if (n0 + n < NUK) {          // NUK % 4 == 0: float4-granular guard exact
        float4 v;
        v.x = R0[em * 68 + n + 0] + R1[em * 68 + n + 0];
        v.y = R0[em * 68 + n + 1] + R1[em * 68 + n + 1];
        v.z = R0[em * 68 + n + 2] + R1[em * 68 + n + 2];
        v.w = R0[em * 68 + n + 3] + R1[em * 68 + n + 3];
        *(float4*)(dst + n) = v;
      }
    }
  }
}

// ---------------------------------------------------------------------------
// Kernel 2b: S = sum of 8 P slices
__global__ __launch_bounds__(256) void gram_reduce_kernel(
    const float* __restrict__ P, float* __restrict__ S)
{
  const int idx = (blockIdx.x * 256 + threadIdx.x) * 4;
  if (idx < NP1) {
    float4 s = *(const float4*)(P + idx);
#pragma unroll
    for (int sl = 1; sl < SPLITK; sl++) {
      const float4 a = *(const float4*)(P + (size_t)sl * NP1 + idx);
      s.x += a.x; s.y += a.y; s.z += a.z; s.w += a.w;
    }
    *(float4*)(S + idx) = s;
  }
}

// ---------------------------------------------------------------------------
// block reductions
__device__ __forceinline__ float blockReduceMax(float v, float* red) {
#pragma unroll
  for (int o = 32; o > 0; o >>= 1) v = fmaxf(v, __shfl_down(v, o));
  if ((threadIdx.x & 63) == 0) red[threadIdx.x >> 6] = v;
  __syncthreads();
  v = fmaxf(fmaxf(red[0], red[1]), fmaxf(red[2], red[3]));
  __syncthreads();
  return v;
}
__device__ __forceinline__ float blockReduceSum(float v, float* red) {
#pragma unroll
  for (int o = 32; o > 0; o >>= 1) v += __shfl_down(v, o);
  if ((threadIdx.x & 63) == 0) red[threadIdx.x >> 6] = v;
  __syncthreads();
  v = red[0] + red[1] + red[2] + red[3];
  __syncthreads();
  return v;
}

// ---------------------------------------------------------------------------
// Kernel 3: softmax over reconstructed scores; emit bf16 coef (rows of CST,
// zero-padded) + cb; zero invalid rows of out.
__global__ __launch_bounds__(256) void softmax_kernel(
    const int* __restrict__ labels, const float* __restrict__ w,
    const float* __restrict__ bbias, const float* __restrict__ sums,
    const float* __restrict__ S, const int* __restrict__ grp_n,
    const int* __restrict__ members, const int* __restrict__ posArr,
    unsigned short* __restrict__ coefh, float* __restrict__ cb,
    float* __restrict__ out)
{
  const int i = blockIdx.x;
  const int t = threadIdx.x;
  const int g = labels[i];
  if (g < 0) {
    const float4 z = make_float4(0.f, 0.f, 0.f, 0.f);
    float4* orow = (float4*)(out + (size_t)i * HW_);
    for (int cidx = t; cidx < HW_ / 4; cidx += 256) orow[cidx] = z;
    return;
  }
  __shared__ float red[4];
  const int n   = grp_n[g];
  const int jq  = i % TC_;
  const int uqi = (i / TC_) * C_ + jq / 3;
  const float wq = w[jq], bq = bbias[jq];
  const float sq = sums[uqi];
  const float* Srow = S + (size_t)uqi * NUK;

  const int jj0 = t, jj1 = t + 256;
  float s0 = -FLT_MAX, s1 = -FLT_MAX;
  if (jj0 < n) {
    const int j = members[g * MAXG + jj0];
    const int rk = j + BC_;
    const int jk = rk % TC_;
    const int uk = (rk / TC_) * C_ + jk / 3;
    s0 = wq * w[jk] * Srow[uk - UK0] + (wq * bbias[jk]) * sq +
         (bq * w[jk]) * sums[uk] + (bq * bbias[jk]) * 4096.f;
  }
  if (jj1 < n) {
    const int j = members[g * MAXG + jj1];
    const int rk = j + BC_;
    const int jk = rk % TC_;
    const int uk = (rk / TC_) * C_ + jk / 3;
    s1 = wq * w[jk] * Srow[uk - UK0] + (wq * bbias[jk]) * sq +
         (bq * w[jk]) * sums[uk] + (bq * bbias[jk]) * 4096.f;
  }
  const float mx = blockReduceMax(fmaxf(s0, s1), red);
  const float e0 = (jj0 < n) ? expf(s0 - mx) : 0.f;
  const float e1 = (jj1 < n) ? expf(s1 - mx) : 0.f;
  const float tot = blockReduceSum(e0 + e1, red);
  const float inv = 1.f / tot;

  const int pos = posArr[i];
  unsigned short* crow = coefh + ((size_t)g * MCAP + pos) * CST;
  float lcb = 0.f;
  if (jj0 < n) {
    const int j = members[g * MAXG + jj0];
    const int jv = (j + 2 * BC_) % TC_;
    const float wgt = e0 * inv;
    if (pos < MCAP && jj0 < CST) crow[jj0] = f32_to_bf16_rne(wgt * w[jv]);
    lcb += wgt * bbias[jv];
  } else if (pos < MCAP && jj0 < CST) {
    crow[jj0] = 0;                 // zero-pad K columns n..CST-1
  }
  if (jj1 < n) {
    const int j = members[g * MAXG + jj1];
    const int jv = (j + 2 * BC_) % TC_;
    const float wgt = e1 * inv;
    lcb += wgt * bbias[jv];        // jj1 >= 256 > CST: never stored in coefh
  }
  const float cbi = blockReduceSum(lcb, red);
  if (t == 0) cb[i] = cbi;
}

// ---------------------------------------------------------------------------
// Kernel 4: out rows of group g = coef[g] (n x K) @ B^T where B[col][k] =
// bf16(x[uv_k][col]). Block = (g, 64-col chunk). B-tile gathered from fp32 x
// with float4 coalesced reads + register transpose + ds_write_b128 (R9's
// ds_write_u16 gather caused 1.13M bank-conflict cycles). A fragments direct
// from global (K-contiguous).
__global__ __launch_bounds__(256) void out_mfma_kernel(
    const float* __restrict__ x, const unsigned short* __restrict__ coefh,
    const float* __restrict__ cb, const int* __restrict__ grp_n,
    const int* __restrict__ members, float* __restrict__ out)
{
  const int g  = blockIdx.x;
  const int c0 = blockIdx.y * 64;
  const int n  = min(grp_n[g], MCAP);
  if (n == 0) return;
  const int Kceil = (n + 31) & ~31;   // multiple of 32; <= 192
  const int nk8 = Kceil >> 3;         // 8-wide k-chunks; <= 24
  const int t = threadIdx.x;
  const int wave = t >> 6;
  const int lane = t & 63;
  const int fr = lane & 15;
  const int fq = lane >> 4;

  __shared__ unsigned short Bt[64][BKP];
  __shared__ int   mem[MCAP];
  __shared__ float cbs[MCAP];

  if (t < n) {
    const int j = members[g * MAXG + t];
    mem[t] = j;
    cbs[t] = cb[j];
  }
  __syncthreads();

  // gather B tile: Bt[col][k] = bf16(x[uv_k][c0+col]).
  // Thread (colq = t&15, kc = t>>4): reads 8 float4s (rows uv_{kc*8+j}, cols
  // colq*4..+3 — a wave reads 4 rows x 256B contiguous), register-transposes,
  // writes 4 ds_write_b128 (Bt rows colq*4+c, k-range kc*8..+7).
  {
    const int colq = t & 15;
    const int kcb  = t >> 4;
    for (int kc = kcb; kc < nk8; kc += 16) {
      float4 vals[8];
#pragma unroll
      for (int j = 0; j < 8; j++) {
        const int k = kc * 8 + j;
        if (k < n) {
          const int jm = mem[k];
          const int rv = jm + 2 * BC_;
          const int uv = (rv / TC_) * C_ + (rv % TC_) / 3;
          vals[j] = *(const float4*)(x + (size_t)uv * HW_ + c0 + colq * 4);
        } else {
          vals[j] = make_float4(0.f, 0.f, 0.f, 0.f);
        }
      }
#pragma unroll
      for (int c = 0; c < 4; c++) {
        short8 pk;
        pk[0] = (short)f32_to_bf16_rne(c == 0 ? vals[0].x : c == 1 ? vals[0].y : c == 2 ? vals[0].z : vals[0].w);
        pk[1] = (short)f32_to_bf16_rne(c == 0 ? vals[1].x : c == 1 ? vals[1].y : c == 2 ? vals[1].z : vals[1].w);
        pk[2] = (short)f32_to_bf16_rne(c == 0 ? vals[2].x : c == 1 ? vals[2].y : c == 2 ? vals[2].z : vals[2].w);
        pk[3] = (short)f32_to_bf16_rne(c == 0 ? vals[3].x : c == 1 ? vals[3].y : c == 2 ? vals[3].z : vals[3].w);
        pk[4] = (short)f32_to_bf16_rne(c == 0 ? vals[4].x : c == 1 ? vals[4].y : c == 2 ? vals[4].z : vals[4].w);
        pk[5] = (short)f32_to_bf16_rne(c == 0 ? vals[5].x : c == 1 ? vals[5].y : c == 2 ? vals[5].z : vals[5].w);
        pk[6] = (short)f32_to_bf16_rne(c == 0 ? vals[6].x : c == 1 ? vals[6].y : c == 2 ? vals[6].z : vals[6].w);
        pk[7] = (short)f32_to_bf16_rne(c == 0 ? vals[7].x : c == 1 ? vals[7].y : c == 2 ? vals[7].z : vals[7].w);
        *(short8*)&Bt[colq * 4 + c][kc * 8] = pk;
      }
    }
  }
  __syncthreads();

  const int colw = wave * 16 + fr;

  for (int m0 = 0; m0 < n; m0 += 32) {
    floatx4 acc0 = (floatx4)(0.f), acc1 = (floatx4)(0.f);
    const unsigned short* pa0 = coefh + ((size_t)g * MCAP + m0 + fr) * CST + fq * 8;
    const unsigned short* pa1 = pa0 + 16 * CST;
    for (int k = 0; k < Kceil; k += 32) {
      const short8 a0 = *(const short8*)(pa0 + k);
      const short8 a1 = *(const short8*)(pa1 + k);
      const short8 b  = *(const short8*)&Bt[colw][fq * 8 + k];
      acc0 = __builtin_amdgcn_mfma_f32_16x16x32_bf16(a0, b, acc0, 0, 0, 0);
      acc1 = __builtin_amdgcn_mfma_f32_16x16x32_bf16(a1, b, acc1, 0, 0, 0);
    }
#pragma unroll
    for (int r = 0; r < 4; r++) {
      int m = m0 + fq * 4 + r;
      if (m < n) out[(size_t)mem[m] * HW_ + c0 + colw] = acc0[r] + cbs[m];
      m += 16;
      if (m < n) out[(size_t)mem[m] * HW_ + c0 + colw] = acc1[r] + cbs[m];
    }
  }
}

// ---------------------------------------------------------------------------
extern "C" void kernel_launch(void* const* d_in, const int* in_sizes, int n_in,
                              void* d_out, int out_size, void* d_ws, size_t ws_size,
                              hipStream_t stream)
{
  const float* x      = (const float*)d_in[0];
  const int*   labels = (const int*)d_in[1];
  const float* w      = (const float*)d_in[2];
  const float* bb     = (const float*)d_in[3];
  float* out = (float*)d_out;

  // workspace carve: ~40.4 MB total (< proven-working 41.0 MB envelope)
  char* wsb = (char*)d_ws;
  size_t off = 0;
  auto carve = [&](size_t bytes) -> void* {
    off = (off + 255) & ~(size_t)255;
    void* p = wsb + off;
    off += bytes;
    return p;
  };
  float* sums    = (float*)carve(NXU * sizeof(float));
  float* S       = (float*)carve((size_t)NP1 * sizeof(float));
  float* P       = (float*)carve((size_t)SPLITK * NP1 * sizeof(float));
  int*   grp_n   = (int*)carve(NG_ * sizeof(int));
  int*   members = (int*)carve((size_t)NG_ * MAXG * sizeof(int));
  int*   posArr  = (int*)carve(BC_ * sizeof(int));
  unsigned short* coefh = (unsigned short*)carve((size_t)NG_ * MCAP * CST * sizeof(unsigned short));
  float* cb      = (float*)carve(BC_ * sizeof(float));
  unsigned short* xhi = (unsigned short*)carve((size_t)NXU * HW_ * sizeof(unsigned short));
  unsigned short* xlo = (unsigned short*)carve((size_t)NXU * HW_ * sizeof(unsigned short));

  conv_kernel<<<NXU, 256, 0, stream>>>(x, xhi, xlo, sums);
  group_build_kernel<<<NG_, 256, 0, stream>>>(labels, grp_n, members, posArr);
  gram_mfma_kernel<<<NTILES * SPLITK, 256, 0, stream>>>(xhi, xlo, P);
  gram_reduce_kernel<<<(NP1 / 4 + 255) / 256, 256, 0, stream>>>(P, S);
  softmax_kernel<<<BC_, 256, 0, stream>>>(labels, w, bb, sums, S, grp_n,
                                          members, posArr, coefh, cb, out);
  out_mfma_kernel<<<dim3(NG_, HW_ / 64), 256, 0, stream>>>(
      x, coefh, cb, grp_n, members, out);
}